// Round 6
// baseline (41.747 us; speedup 1.0000x reference)
//
#include <hip/hip_runtime.h>
#include <hip/hip_bf16.h>

#define LL 50
#define DD 64
#define NCATS 1000
#define NRAT 5

// ws byte offsets
#define OFF_H    0          // ushort[1000*5*64] = 640000 B
#define OFF_M1T  640000     // ushort[64*64] bf16 (M1t[d][e] = (Wq Wk^T)[e][d])
#define OFF_WVOT 648192     // ushort[64*64] bf16 (Wvot[d][e] = (Wv Wo)[e][d])
#define OFF_BKQ  656384     // float[64]  (Wk @ bq)
#define OFF_BVO  656640     // float[64]  (bv @ Wo + bo)

typedef __attribute__((ext_vector_type(8))) short short8;
typedef __attribute__((ext_vector_type(4))) float f32x4;

union U4S8 { uint4 u4; short8 s8; };

__device__ __forceinline__ float rlanef(float v, int l) {
  return __uint_as_float(__builtin_amdgcn_readlane(__float_as_uint(v), l));
}
__device__ __forceinline__ unsigned short f2bf(float f) {  // RNE f32->bf16
  unsigned int u = __float_as_uint(f);
  u = (u + 0x7fffu + ((u >> 16) & 1u)) >> 16;
  return (unsigned short)u;
}
__device__ __forceinline__ unsigned int pk2bf(float lo, float hi) {
  return (unsigned int)f2bf(lo) | ((unsigned int)f2bf(hi) << 16);
}

// ---------------- prep: all tables, one kernel, independent 1-wave blocks ----------------
__global__ __launch_bounds__(64) void prep_kernel(
    const float* __restrict__ c2e, const float* __restrict__ r2e,
    const float* __restrict__ W1, const float* __restrict__ b1,
    const float* __restrict__ Wq, const float* __restrict__ bq,
    const float* __restrict__ Wk, const float* __restrict__ Wv,
    const float* __restrict__ Wo, const float* __restrict__ bv,
    const float* __restrict__ bo, char* __restrict__ ws) {
  const int lane = threadIdx.x;
  const int b = blockIdx.x;
  unsigned short* H = (unsigned short*)(ws + OFF_H);
  unsigned short* M1T = (unsigned short*)(ws + OFF_M1T);
  unsigned short* WVOT = (unsigned short*)(ws + OFF_WVOT);
  float* BKQ = (float*)(ws + OFF_BKQ);
  float* BVO = (float*)(ws + OFF_BVO);

  if (b < NCATS) {
    const int vc = b;
    const float* __restrict__ crow = c2e + (size_t)vc * DD;
    float av = 0.f;
#pragma unroll 8
    for (int e = 0; e < DD; ++e) av = fmaf(crow[e], W1[e * DD + lane], av);
#pragma unroll
    for (int r = 0; r < NRAT; ++r) {
      const float* __restrict__ rrow = r2e + (size_t)r * DD;
      float hb = b1[lane];
#pragma unroll 8
      for (int e = 0; e < DD; ++e) hb = fmaf(rrow[e], W1[(DD + e) * DD + lane], hb);
      H[((size_t)vc * NRAT + r) * DD + lane] = f2bf(fmaxf(av + hb, 0.f));
    }
  } else if (b < 1064) {
    const int d = b - 1000;
    float acc = 0.f;
#pragma unroll 8
    for (int t = 0; t < DD; ++t) acc = fmaf(Wq[lane * DD + t], Wk[d * DD + t], acc);
    M1T[d * DD + lane] = f2bf(acc);
  } else if (b < 1128) {
    const int d = b - 1064;
    float acc = 0.f;
#pragma unroll 8
    for (int t = 0; t < DD; ++t) acc = fmaf(Wv[lane * DD + t], Wo[t * DD + d], acc);
    WVOT[d * DD + lane] = f2bf(acc);
  } else {
    float a1 = 0.f, a2 = bo[lane];
#pragma unroll 8
    for (int t = 0; t < DD; ++t) {
      a1 = fmaf(Wk[lane * DD + t], bq[t], a1);
      a2 = fmaf(bv[t], Wo[t * DD + lane], a2);
    }
    BKQ[lane] = a1;
    BVO[lane] = a2;
  }
}

// ---------------- main: 512 threads, 16 nodes per block, 2 nodes per wave ----------------
__global__ __launch_bounds__(512, 8) void vc_main(
    const int* __restrict__ nodes, const int* __restrict__ hvc,
    const int* __restrict__ hr, const float* __restrict__ v2e,
    const char* __restrict__ ws, float* __restrict__ out, int N) {
  const unsigned short* __restrict__ H = (const unsigned short*)(ws + OFF_H);
  const unsigned short* __restrict__ M1T = (const unsigned short*)(ws + OFF_M1T);
  const unsigned short* __restrict__ WVOT = (const unsigned short*)(ws + OFF_WVOT);
  const float* __restrict__ BKQ = (const float*)(ws + OFF_BKQ);
  const float* __restrict__ BVO = (const float*)(ws + OFF_BVO);

  __shared__ float gS[16][68];    // [node][d]; 68-stride keeps float4 alignment, 2-way alias max
  __shared__ float ctxS[16][68];

  const int tid = threadIdx.x;
  const int wid = tid >> 6;    // 0..7
  const int lane = tid & 63;
  const int kg = lane >> 4;    // 0..3
  const int rw = lane & 15;    // 0..15
  const int nb = blockIdx.x * 16;

  // ---- prefetch this wave's 2 nodes' history indices (lane = history slot) ----
  const int lidx = (lane < LL) ? lane : 0;
  const int nA = min(nb + wid * 2 + 0, N - 1);
  const int nB = min(nb + wid * 2 + 1, N - 1);
  const int idxA = hvc[(size_t)nA * LL + lidx] * NRAT + hr[(size_t)nA * LL + lidx];
  const int idxB = hvc[(size_t)nB * LL + lidx] * NRAT + hr[(size_t)nB * LL + lidx];

  // ---- G = X @ M1 + bkq : waves 0-3, wave w computes d-quarter n0==w ----
  if (wid < 4) {
    const int node_id = nodes[min(nb + rw, N - 1)];
    const float* __restrict__ xrow = v2e + (size_t)node_id * DD;
    short8 xa[2];
#pragma unroll
    for (int ks = 0; ks < 2; ++ks) {
      const float4 f0 = *(const float4*)(xrow + ks * 32 + kg * 8);
      const float4 f1 = *(const float4*)(xrow + ks * 32 + kg * 8 + 4);
      U4S8 t;
      t.u4.x = pk2bf(f0.x, f0.y); t.u4.y = pk2bf(f0.z, f0.w);
      t.u4.z = pk2bf(f1.x, f1.y); t.u4.w = pk2bf(f1.z, f1.w);
      xa[ks] = t.s8;
    }
    const int n0 = wid;
    f32x4 a = {0.f, 0.f, 0.f, 0.f};
#pragma unroll
    for (int ks = 0; ks < 2; ++ks) {
      const short8 bf = *(const short8*)(M1T + (n0 * 16 + rw) * DD + ks * 32 + kg * 8);
      a = __builtin_amdgcn_mfma_f32_16x16x32_bf16(xa[ks], bf, a, 0, 0, 0);
    }
    const float bkqv = BKQ[n0 * 16 + rw];
#pragma unroll
    for (int r = 0; r < 4; ++r) gS[kg * 4 + r][n0 * 16 + rw] = a[r] + bkqv;
  }
  __syncthreads();

  // ---- per-node gather phases: 2 nodes per wave ----
#pragma unroll
  for (int nn = 0; nn < 2; ++nn) {
    const int idx = nn ? idxB : idxA;
    const int myrow = wid * 2 + nn;

    // A-frag: g (bf16), replicated across all 16 rows (lane-invariant in rw)
    short8 ga[2];
#pragma unroll
    for (int ks = 0; ks < 2; ++ks) {
      const float* __restrict__ gp = &gS[myrow][ks * 32 + kg * 8];
      const float4 f0 = *(const float4*)(gp);
      const float4 f1 = *(const float4*)(gp + 4);
      U4S8 t;
      t.u4.x = pk2bf(f0.x, f0.y); t.u4.y = pk2bf(f0.z, f0.w);
      t.u4.z = pk2bf(f1.x, f1.y); t.u4.w = pk2bf(f1.z, f1.w);
      ga[ks] = t.s8;
    }

    // B-frag row indices: lane (kg,rw) serves history slot l = lt*16 + rw
    int bidx[4];
#pragma unroll
    for (int lt = 0; lt < 4; ++lt) bidx[lt] = __shfl(idx, lt * 16 + rw, 64);

    // scores via MFMA: C[*][col=rw] = sum_k g[k] * H[idx_col][k]  (all rows equal)
    float s0, s1, s2, s3;
    {
      f32x4 a;
#pragma unroll
      for (int lt = 0; lt < 4; ++lt) {
        a = (f32x4){0.f, 0.f, 0.f, 0.f};
#pragma unroll
        for (int ks = 0; ks < 2; ++ks) {
          U4S8 hb;
          hb.u4 = *(const uint4*)(H + (size_t)bidx[lt] * DD + ks * 32 + kg * 8);
          a = __builtin_amdgcn_mfma_f32_16x16x32_bf16(ga[ks], hb.s8, a, 0, 0, 0);
        }
        if (lt == 0) s0 = a[0];
        else if (lt == 1) s1 = a[0];
        else if (lt == 2) s2 = a[0];
        else s3 = a[0];
      }
    }
    s0 *= 0.125f; s1 *= 0.125f; s2 *= 0.125f;
    s3 = (rw < 2) ? s3 * 0.125f : -INFINITY;   // l = 48+rw valid only for rw<2

    // softmax over 50 slots: local 4-reg reduce + 16-lane group reduce
    float m = fmaxf(fmaxf(s0, s1), fmaxf(s2, s3));
#pragma unroll
    for (int x = 1; x <= 8; x <<= 1) m = fmaxf(m, __shfl_xor(m, x, 64));
    float e0 = __expf(s0 - m), e1 = __expf(s1 - m), e2 = __expf(s2 - m);
    float e3 = (rw < 2) ? __expf(s3 - m) : 0.f;
    float Z = ((e0 + e1) + (e2 + e3));
#pragma unroll
    for (int x = 1; x <= 8; x <<= 1) Z += __shfl_xor(Z, x, 64);
    const float invZ = 1.f / Z;

    // ctx: lane = d; 4 static blocks keyed to e0..e3 (readlane idx is uniform SGPR)
    float c0 = 0.f, c1 = 0.f;
#define CTX_BLOCK(EREG, BASE, CNT, CACC)                                   \
    _Pragma("unroll 4")                                                    \
    for (int j = 0; j < (CNT); ++j) {                                      \
      const int l = (BASE) + j;                                            \
      const int si = __builtin_amdgcn_readlane(idx, l);                    \
      const float el = rlanef(EREG, j);                                    \
      const unsigned short hbb = H[(size_t)si * DD + lane];                \
      CACC = fmaf(__uint_as_float(((unsigned int)hbb) << 16), el, CACC);   \
    }
    CTX_BLOCK(e0, 0, 16, c0)
    CTX_BLOCK(e1, 16, 16, c1)
    CTX_BLOCK(e2, 32, 16, c0)
    CTX_BLOCK(e3, 48, 2, c1)
#undef CTX_BLOCK
    ctxS[myrow][lane] = (c0 + c1) * invZ;
  }
  __syncthreads();

  // ---- OUT = CTX @ Wvo + bvo : waves 0-3, wave w computes d-quarter n0==w ----
  if (wid < 4) {
    short8 ca[2];
#pragma unroll
    for (int ks = 0; ks < 2; ++ks) {
      const float* __restrict__ cp = &ctxS[rw][ks * 32 + kg * 8];
      const float4 f0 = *(const float4*)(cp);
      const float4 f1 = *(const float4*)(cp + 4);
      U4S8 t;
      t.u4.x = pk2bf(f0.x, f0.y); t.u4.y = pk2bf(f0.z, f0.w);
      t.u4.z = pk2bf(f1.x, f1.y); t.u4.w = pk2bf(f1.z, f1.w);
      ca[ks] = t.s8;
    }
    const int n0 = wid;
    f32x4 a = {0.f, 0.f, 0.f, 0.f};
#pragma unroll
    for (int ks = 0; ks < 2; ++ks) {
      const short8 bf = *(const short8*)(WVOT + (n0 * 16 + rw) * DD + ks * 32 + kg * 8);
      a = __builtin_amdgcn_mfma_f32_16x16x32_bf16(ca[ks], bf, a, 0, 0, 0);
    }
    const float bvov = BVO[n0 * 16 + rw];
#pragma unroll
    for (int r = 0; r < 4; ++r) {
      const int node = nb + kg * 4 + r;
      if (node < N) out[(size_t)node * DD + n0 * 16 + rw] = a[r] + bvov;
    }
  }
}

extern "C" void kernel_launch(void* const* d_in, const int* in_sizes, int n_in,
                              void* d_out, int out_size, void* d_ws, size_t ws_size,
                              hipStream_t stream) {
  const int* nodes = (const int*)d_in[0];
  const int* hvc = (const int*)d_in[1];
  const int* hr = (const int*)d_in[2];
  const float* c2e = (const float*)d_in[3];
  const float* v2e = (const float*)d_in[4];
  const float* r2e = (const float*)d_in[5];
  const float* W1 = (const float*)d_in[6];
  const float* b1 = (const float*)d_in[7];
  const float* Wq = (const float*)d_in[8];
  const float* bq = (const float*)d_in[9];
  const float* Wk = (const float*)d_in[10];
  const float* bk = (const float*)d_in[11];  // unused: q·bk cancels in softmax
  const float* Wv = (const float*)d_in[12];
  const float* bv = (const float*)d_in[13];
  const float* Wo = (const float*)d_in[14];
  const float* bo = (const float*)d_in[15];
  (void)bk;
  float* out = (float*)d_out;
  char* ws = (char*)d_ws;

  const int N = in_sizes[0];

  prep_kernel<<<1129, 64, 0, stream>>>(c2e, r2e, W1, b1, Wq, bq, Wk, Wv, Wo, bv, bo, ws);
  vc_main<<<(N + 15) / 16, 512, 0, stream>>>(nodes, hvc, hr, v2e, ws, out, N);
}

// Round 8
// 40.891 us; speedup vs baseline: 1.0209x; 1.0209x over previous
//
#include <hip/hip_runtime.h>
#include <hip/hip_bf16.h>

#define LL 50
#define DD 64
#define NCATS 1000
#define NRAT 5

// ws byte offsets
#define OFF_H    0          // ushort[1000*5*64] = 640000 B (bf16 H table)
#define OFF_M1T  640000     // ushort[64*64] bf16 (M1t[d][e] = (Wq Wk^T)[e][d])
#define OFF_WVOT 648192     // ushort[64*64] bf16 (Wvot[d][e] = (Wv Wo)[e][d])
#define OFF_BKQ  656384     // float[64]  (Wk @ bq)
#define OFF_BVO  656640     // float[64]  (bv @ Wo + bo)

typedef __attribute__((ext_vector_type(8))) short short8;
typedef __attribute__((ext_vector_type(4))) float f32x4;

union U4S8 { uint4 u4; short8 s8; };

__device__ __forceinline__ float rlanef(float v, int l) {
  return __uint_as_float(__builtin_amdgcn_readlane(__float_as_uint(v), l));
}
__device__ __forceinline__ unsigned short f2bf(float f) {  // RNE f32->bf16
  unsigned int u = __float_as_uint(f);
  u = (u + 0x7fffu + ((u >> 16) & 1u)) >> 16;
  return (unsigned short)u;
}
__device__ __forceinline__ unsigned int pk2bf(float lo, float hi) {
  return (unsigned int)f2bf(lo) | ((unsigned int)f2bf(hi) << 16);
}

// ---------------- prep: all tables, one kernel, independent 1-wave blocks ----------------
__global__ __launch_bounds__(64) void prep_kernel(
    const float* __restrict__ c2e, const float* __restrict__ r2e,
    const float* __restrict__ W1, const float* __restrict__ b1,
    const float* __restrict__ Wq, const float* __restrict__ bq,
    const float* __restrict__ Wk, const float* __restrict__ Wv,
    const float* __restrict__ Wo, const float* __restrict__ bv,
    const float* __restrict__ bo, char* __restrict__ ws) {
  const int lane = threadIdx.x;
  const int b = blockIdx.x;
  unsigned short* H = (unsigned short*)(ws + OFF_H);
  unsigned short* M1T = (unsigned short*)(ws + OFF_M1T);
  unsigned short* WVOT = (unsigned short*)(ws + OFF_WVOT);
  float* BKQ = (float*)(ws + OFF_BKQ);
  float* BVO = (float*)(ws + OFF_BVO);

  if (b < NCATS) {
    const int vc = b;
    const float* __restrict__ crow = c2e + (size_t)vc * DD;
    float av = 0.f;
#pragma unroll 8
    for (int e = 0; e < DD; ++e) av = fmaf(crow[e], W1[e * DD + lane], av);
#pragma unroll
    for (int r = 0; r < NRAT; ++r) {
      const float* __restrict__ rrow = r2e + (size_t)r * DD;
      float hb = b1[lane];
#pragma unroll 8
      for (int e = 0; e < DD; ++e) hb = fmaf(rrow[e], W1[(DD + e) * DD + lane], hb);
      H[((size_t)vc * NRAT + r) * DD + lane] = f2bf(fmaxf(av + hb, 0.f));
    }
  } else if (b < 1064) {
    const int d = b - 1000;
    float acc = 0.f;
#pragma unroll 8
    for (int t = 0; t < DD; ++t) acc = fmaf(Wq[lane * DD + t], Wk[d * DD + t], acc);
    M1T[d * DD + lane] = f2bf(acc);
  } else if (b < 1128) {
    const int d = b - 1064;
    float acc = 0.f;
#pragma unroll 8
    for (int t = 0; t < DD; ++t) acc = fmaf(Wv[lane * DD + t], Wo[t * DD + d], acc);
    WVOT[d * DD + lane] = f2bf(acc);
  } else {
    float a1 = 0.f, a2 = bo[lane];
#pragma unroll 8
    for (int t = 0; t < DD; ++t) {
      a1 = fmaf(Wk[lane * DD + t], bq[t], a1);
      a2 = fmaf(bv[t], Wo[t * DD + lane], a2);
    }
    BKQ[lane] = a1;
    BVO[lane] = a2;
  }
}

// ---------------- main: 256 threads, 4 nodes per block, 1 node per wave ----------------
// Per wave: async-stage the node's 50 H rows (bf16, 128B each) into LDS via
// global_load_lds (7 instrs, source chunk-swizzled by slot&7), then scores-MFMA
// and ctx read LDS only.
__global__ __launch_bounds__(256, 5) void vc_main(
    const int* __restrict__ nodes, const int* __restrict__ hvc,
    const int* __restrict__ hr, const float* __restrict__ v2e,
    const char* __restrict__ ws, float* __restrict__ out, int N) {
  const unsigned short* __restrict__ H = (const unsigned short*)(ws + OFF_H);
  const unsigned short* __restrict__ M1T = (const unsigned short*)(ws + OFF_M1T);
  const unsigned short* __restrict__ WVOT = (const unsigned short*)(ws + OFF_WVOT);
  const float* __restrict__ BKQ = (const float*)(ws + OFF_BKQ);
  const float* __restrict__ BVO = (const float*)(ws + OFF_BVO);

  // manual carve: H-stage overflow reads (masked slots 50..63) stay in-array
  __shared__ __align__(16) char smem[25600 + 1088 + 1088];
  char* HlB = smem;                          // 4 waves x 50 rows x 128B, swizzled
  float* gS = (float*)(smem + 25600);        // [4][68] f32
  float* ctxS = (float*)(smem + 25600 + 1088);  // [4][68] f32

  const int tid = threadIdx.x;
  const int wid = tid >> 6;    // 0..3  (= node within block, = d-quarter n0)
  const int lane = tid & 63;
  const int kg = lane >> 4;    // 0..3
  const int rw = lane & 15;    // 0..15
  const int nb = blockIdx.x * 4;
  const int n = min(nb + wid, N - 1);

  // ---- history indices: lane l <-> slot l ----
  const int lidx = (lane < LL) ? lane : 0;
  const int idx = hvc[(size_t)n * LL + lidx] * NRAT + hr[(size_t)n * LL + lidx];

  // ---- async stage: 7 x global_load_lds, each = 8 rows (64 lanes x 16B) ----
  // LDS dest is linear (slot*128 + chunk*16); SOURCE chunk is pre-swizzled by
  // (slot&7) so swizzled LDS reads are conflict-spread (guide #21 / m173).
  {
    const int chunk = lane & 7;
    char* wbase = HlB + wid * 6400;
#pragma unroll
    for (int i = 0; i < 7; ++i) {
      const int s = (i < 6) ? (i * 8 + (lane >> 3)) : (42 + (lane >> 3));
      const int sidx = __shfl(idx, s, 64);
      const char* src = (const char*)H + (size_t)sidx * 128 + ((chunk ^ (s & 7)) << 4);
      __builtin_amdgcn_global_load_lds(
          (const __attribute__((address_space(1))) void*)src,
          (__attribute__((address_space(3))) void*)(wbase + ((i < 6) ? i * 1024 : 5376)),
          16, 0, 0);
    }
  }

  // ---- G = X @ M1 + bkq : wave wid computes d-quarter n0==wid for the 4 nodes ----
  {
    const int node_id = nodes[min(nb + (rw & 3), N - 1)];
    const float* __restrict__ xrow = v2e + (size_t)node_id * DD;
    short8 xa[2];
#pragma unroll
    for (int ks = 0; ks < 2; ++ks) {
      const float4 f0 = *(const float4*)(xrow + ks * 32 + kg * 8);
      const float4 f1 = *(const float4*)(xrow + ks * 32 + kg * 8 + 4);
      U4S8 t;
      t.u4.x = pk2bf(f0.x, f0.y); t.u4.y = pk2bf(f0.z, f0.w);
      t.u4.z = pk2bf(f1.x, f1.y); t.u4.w = pk2bf(f1.z, f1.w);
      xa[ks] = t.s8;
    }
    const int n0 = wid;
    f32x4 a = {0.f, 0.f, 0.f, 0.f};
#pragma unroll
    for (int ks = 0; ks < 2; ++ks) {
      const short8 bf = *(const short8*)(M1T + (n0 * 16 + rw) * DD + ks * 32 + kg * 8);
      a = __builtin_amdgcn_mfma_f32_16x16x32_bf16(xa[ks], bf, a, 0, 0, 0);
    }
    if (kg == 0) {   // C rows 0..3 = nodes 0..3
      const float bkqv = BKQ[n0 * 16 + rw];
#pragma unroll
      for (int r = 0; r < 4; ++r) gS[r * 68 + n0 * 16 + rw] = a[r] + bkqv;
    }
  }
  __syncthreads();
  asm volatile("s_waitcnt vmcnt(0)" ::: "memory");  // H-stage complete
  __builtin_amdgcn_sched_barrier(0);

  const unsigned short* __restrict__ wH = (const unsigned short*)(HlB + wid * 6400);

  // ---- scores via MFMA from LDS: A = g replicated, B cols = H rows (swizzled read) ----
  short8 ga[2];
#pragma unroll
  for (int ks = 0; ks < 2; ++ks) {
    const float* __restrict__ gp = gS + wid * 68 + ks * 32 + kg * 8;
    const float4 f0 = *(const float4*)(gp);
    const float4 f1 = *(const float4*)(gp + 4);
    U4S8 t;
    t.u4.x = pk2bf(f0.x, f0.y); t.u4.y = pk2bf(f0.z, f0.w);
    t.u4.z = pk2bf(f1.x, f1.y); t.u4.w = pk2bf(f1.z, f1.w);
    ga[ks] = t.s8;
  }
  float s0, s1, s2, s3;
  {
    f32x4 a;
#pragma unroll
    for (int lt = 0; lt < 4; ++lt) {
      const int s = lt * 16 + rw;         // history slot served by this B column
      a = (f32x4){0.f, 0.f, 0.f, 0.f};
#pragma unroll
      for (int ks = 0; ks < 2; ++ks) {
        const int c = (ks * 4 + kg) ^ (s & 7);   // swizzled 16B chunk
        U4S8 hb;
        hb.u4 = *(const uint4*)(wH + s * 64 + c * 8);
        a = __builtin_amdgcn_mfma_f32_16x16x32_bf16(ga[ks], hb.s8, a, 0, 0, 0);
      }
      if (lt == 0) s0 = a[0];
      else if (lt == 1) s1 = a[0];
      else if (lt == 2) s2 = a[0];
      else s3 = a[0];
    }
  }
  s0 *= 0.125f; s1 *= 0.125f; s2 *= 0.125f;
  s3 = (rw < 2) ? s3 * 0.125f : -INFINITY;   // slots 48,49 only (q.bk cancels in softmax)

  // ---- softmax over 50 slots: 4-reg local + 16-lane-group reduce ----
  float m = fmaxf(fmaxf(s0, s1), fmaxf(s2, s3));
#pragma unroll
  for (int x = 1; x <= 8; x <<= 1) m = fmaxf(m, __shfl_xor(m, x, 64));
  float e0 = __expf(s0 - m), e1 = __expf(s1 - m), e2 = __expf(s2 - m);
  float e3 = (rw < 2) ? __expf(s3 - m) : 0.f;
  float Z = ((e0 + e1) + (e2 + e3));
#pragma unroll
  for (int x = 1; x <= 8; x <<= 1) Z += __shfl_xor(Z, x, 64);
  const float invZ = 1.f / Z;

  // ---- ctx[d=lane] = sum_l e_l * H[slot l][d] / Z, all from LDS ----
  {
    const int sub = (lane & 7) * 2;
    const int hi3 = lane >> 3;
    float c0 = 0.f, c1 = 0.f;
#define CTX_BLOCK(EREG, BASE, CNT, CACC)                                        \
    _Pragma("unroll")                                                           \
    for (int j = 0; j < (CNT); ++j) {                                           \
      const int l = (BASE) + j;                                                 \
      const unsigned short hbb = *(const unsigned short*)(                      \
          (const char*)wH + l * 128 + (((hi3 ^ (l & 7)) << 4) | sub));          \
      CACC = fmaf(__uint_as_float(((unsigned int)hbb) << 16),                   \
                  rlanef(EREG, j), CACC);                                       \
    }
    CTX_BLOCK(e0, 0, 16, c0)
    CTX_BLOCK(e1, 16, 16, c1)
    CTX_BLOCK(e2, 32, 16, c0)
    CTX_BLOCK(e3, 48, 2, c1)
#undef CTX_BLOCK
    ctxS[wid * 68 + lane] = (c0 + c1) * invZ;
  }
  __syncthreads();

  // ---- OUT = CTX @ Wvo + bvo : wave wid computes d-quarter n0==wid ----
  {
    short8 ca[2];
#pragma unroll
    for (int ks = 0; ks < 2; ++ks) {
      const float* __restrict__ cp = ctxS + (rw & 3) * 68 + ks * 32 + kg * 8;
      const float4 f0 = *(const float4*)(cp);
      const float4 f1 = *(const float4*)(cp + 4);
      U4S8 t;
      t.u4.x = pk2bf(f0.x, f0.y); t.u4.y = pk2bf(f0.z, f0.w);
      t.u4.z = pk2bf(f1.x, f1.y); t.u4.w = pk2bf(f1.z, f1.w);
      ca[ks] = t.s8;
    }
    const int n0 = wid;
    f32x4 a = {0.f, 0.f, 0.f, 0.f};
#pragma unroll
    for (int ks = 0; ks < 2; ++ks) {
      const short8 bf = *(const short8*)(WVOT + (n0 * 16 + rw) * DD + ks * 32 + kg * 8);
      a = __builtin_amdgcn_mfma_f32_16x16x32_bf16(ca[ks], bf, a, 0, 0, 0);
    }
    if (kg == 0) {
      const float bvov = BVO[n0 * 16 + rw];
#pragma unroll
      for (int r = 0; r < 4; ++r) {
        const int node = nb + r;
        if (node < N) out[(size_t)node * DD + n0 * 16 + rw] = a[r] + bvov;
      }
    }
  }
}

extern "C" void kernel_launch(void* const* d_in, const int* in_sizes, int n_in,
                              void* d_out, int out_size, void* d_ws, size_t ws_size,
                              hipStream_t stream) {
  const int* nodes = (const int*)d_in[0];
  const int* hvc = (const int*)d_in[1];
  const int* hr = (const int*)d_in[2];
  const float* c2e = (const float*)d_in[3];
  const float* v2e = (const float*)d_in[4];
  const float* r2e = (const float*)d_in[5];
  const float* W1 = (const float*)d_in[6];
  const float* b1 = (const float*)d_in[7];
  const float* Wq = (const float*)d_in[8];
  const float* bq = (const float*)d_in[9];
  const float* Wk = (const float*)d_in[10];
  const float* bk = (const float*)d_in[11];  // unused: q·bk cancels in softmax
  const float* Wv = (const float*)d_in[12];
  const float* bv = (const float*)d_in[13];
  const float* Wo = (const float*)d_in[14];
  const float* bo = (const float*)d_in[15];
  (void)bk;
  float* out = (float*)d_out;
  char* ws = (char*)d_ws;

  const int N = in_sizes[0];

  prep_kernel<<<1129, 64, 0, stream>>>(c2e, r2e, W1, b1, Wq, bq, Wk, Wv, Wo, bv, bo, ws);
  vc_main<<<(N + 3) / 4, 256, 0, stream>>>(nodes, hvc, hr, v2e, ws, out, N);
}